// Round 1
// baseline (625.343 us; speedup 1.0000x reference)
//
#include <hip/hip_runtime.h>
#include <stdint.h>

typedef unsigned short u16;
typedef __attribute__((ext_vector_type(8))) short bf16x8;
typedef __attribute__((ext_vector_type(4))) float f32x4;

#define LN_THETA 9.210340371976184f
#define SLEN 4096
#define DMODEL 1024

__device__ __forceinline__ u16 f2bf(float f) {
  union { float f; unsigned u; } v; v.f = f;
  unsigned u = v.u;
  return (u16)((u + 0x7FFFu + ((u >> 16) & 1u)) >> 16);
}

__device__ __forceinline__ f32x4 mfma16(bf16x8 a, bf16x8 b, f32x4 c) {
  return __builtin_amdgcn_mfma_f32_16x16x32_bf16(a, b, c, 0, 0, 0);
}

__device__ __forceinline__ void async16(const u16* g, u16* l) {
  __builtin_amdgcn_global_load_lds(
      (const __attribute__((address_space(1))) unsigned int*)g,
      (__attribute__((address_space(3))) unsigned int*)l, 16, 0, 0);
}

// ---- RoPE table: tab[s*32+i] = (cos, sin)(pos[s] * theta^(-2i/64))
__global__ void rope_tab_kernel(const int* __restrict__ tokpos,
                                float2* __restrict__ tab) {
  int t = blockIdx.x * 256 + threadIdx.x;   // 0 .. 4096*32-1
  int s = t >> 5, i = t & 31;
  float inv = expf(-(float)(2 * i) * (LN_THETA / 64.0f));
  float ang = (float)tokpos[s] * inv;
  float sn, cs;
  sincosf(ang, &sn, &cs);
  tab[t] = make_float2(cs, sn);
}

// ---- fp32 -> bf16 (RNE), 4 elems/thread
__global__ void cvt_kernel(const float* __restrict__ src, u16* __restrict__ dst,
                           int n4) {
  int i = blockIdx.x * 256 + threadIdx.x;
  if (i >= n4) return;
  float4 v = ((const float4*)src)[i];
  ushort4 o;
  o.x = f2bf(v.x); o.y = f2bf(v.y); o.z = f2bf(v.z); o.w = f2bf(v.w);
  ((ushort4*)dst)[i] = o;
}

// ---- 128x128 bf16 MFMA GEMM, D = A(MxK) . B(NxK)^T, K=1024.
// EPI 0: plain fp32 store, D[row][col] -> outf, ld = N
// EPI 1: A = W_qkv (rows = e), B = x (rows = s). Fused RoPE, scatter q/k/vT.
template <int EPI>
__global__ __launch_bounds__(256) void gemm128_kernel(
    const u16* __restrict__ A, const u16* __restrict__ B, int N,
    float* __restrict__ outf, u16* __restrict__ qb, u16* __restrict__ kb,
    u16* __restrict__ vbT, const float2* __restrict__ cstab) {
  const int K = 1024;
  __shared__ __align__(16) u16 As[128][32];
  __shared__ __align__(16) u16 Bs[128][32];
  const int tid = threadIdx.x;
  const int wave = tid >> 6, lane = tid & 63;
  const int quad = lane >> 4, col = lane & 15;
  const int rowBase = blockIdx.x * 128;
  const int colBase = blockIdx.y * 128;
  const int wm = (wave >> 1) * 64, wn = (wave & 1) * 64;

  // staging: wave w, inst j cover LDS bytes (w*2+j)*1024 + lane*16 (contiguous)
  const int sRow = wave * 32 + (lane >> 2);
  const int sK = (lane & 3) * 8;
  const u16* gA = A + (size_t)(rowBase + sRow) * K + sK;
  const u16* gB = B + (size_t)(colBase + sRow) * K + sK;

  f32x4 acc[4][4];
#pragma unroll
  for (int i = 0; i < 4; ++i)
#pragma unroll
    for (int j = 0; j < 4; ++j)
      acc[i][j] = f32x4{0.f, 0.f, 0.f, 0.f};

  for (int kk = 0; kk < K; kk += 32) {
    __syncthreads();
    async16(gA + kk, &As[sRow][sK]);
    async16(gA + kk + 16 * K, &As[sRow + 16][sK]);
    async16(gB + kk, &Bs[sRow][sK]);
    async16(gB + kk + 16 * K, &Bs[sRow + 16][sK]);
    __syncthreads();
    bf16x8 af[4], bfr[4];
#pragma unroll
    for (int i = 0; i < 4; ++i)
      af[i] = *(const bf16x8*)&As[wm + i * 16 + col][quad * 8];
#pragma unroll
    for (int j = 0; j < 4; ++j)
      bfr[j] = *(const bf16x8*)&Bs[wn + j * 16 + col][quad * 8];
#pragma unroll
    for (int i = 0; i < 4; ++i)
#pragma unroll
      for (int j = 0; j < 4; ++j)
        acc[i][j] = mfma16(af[i], bfr[j], acc[i][j]);
  }

  if (EPI == 0) {
#pragma unroll
    for (int i = 0; i < 4; ++i) {
      int r0 = rowBase + wm + i * 16 + quad * 4;
#pragma unroll
      for (int j = 0; j < 4; ++j) {
        int cc = colBase + wn + j * 16 + col;
#pragma unroll
        for (int r = 0; r < 4; ++r)
          outf[(size_t)(r0 + r) * N + cc] = acc[i][j][r];
      }
    }
  } else {
    // D[e][s]; lane holds e0..e0+3 (e0 % 4 == 0) for fixed s -> RoPE pairs local
#pragma unroll
    for (int j = 0; j < 4; ++j) {
      int s = colBase + wn + j * 16 + col;
#pragma unroll
      for (int i = 0; i < 4; ++i) {
        int e0 = rowBase + wm + i * 16 + quad * 4;
        int sec = e0 >> 10;          // 0=q 1=k 2=v
        int eh = e0 & 1023;
        int hh = eh >> 6, d = eh & 63;   // d % 4 == 0
        float v0 = acc[i][j][0], v1 = acc[i][j][1];
        float v2 = acc[i][j][2], v3 = acc[i][j][3];
        if (sec < 2) {
          float2 cs0 = cstab[s * 32 + (d >> 1)];
          float2 cs1 = cstab[s * 32 + (d >> 1) + 1];
          float r0 = v0 * cs0.x - v1 * cs0.y;
          float r1 = v1 * cs0.x + v0 * cs0.y;
          float r2 = v2 * cs1.x - v3 * cs1.y;
          float r3 = v3 * cs1.x + v2 * cs1.y;
          u16* dst = (sec == 0 ? qb : kb) + ((size_t)hh * SLEN + s) * 64 + d;
          dst[0] = f2bf(r0); dst[1] = f2bf(r1);
          dst[2] = f2bf(r2); dst[3] = f2bf(r3);
        } else {
          u16* dst = vbT + ((size_t)hh * 64 + d) * SLEN + s;
          dst[0] = f2bf(v0);
          dst[SLEN] = f2bf(v1);
          dst[2 * SLEN] = f2bf(v2);
          dst[3 * SLEN] = f2bf(v3);
        }
      }
    }
  }
}

// ---- causal flash attention, 1 wave = 16 q rows, 32-key chunks
// q,k: [h][s][64] bf16 (RoPE applied); vT: [h][64][s] bf16; out: [s][1024] bf16
__global__ __launch_bounds__(256) void flash_kernel(
    const u16* __restrict__ qbuf, const u16* __restrict__ kbuf,
    const u16* __restrict__ vbT, u16* __restrict__ attn) {
  const int S = SLEN;
  const int h = blockIdx.y;
  const int wave = threadIdx.x >> 6, lane = threadIdx.x & 63;
  const int quad = lane >> 4, col = lane & 15;
  const int qbase = blockIdx.x * 64 + wave * 16;
  const u16* Q = qbuf + (size_t)h * S * 64;
  const u16* Kh = kbuf + (size_t)h * S * 64;
  const u16* Vt = vbT + (size_t)h * 64 * S;

  __shared__ __align__(16) u16 Pld[4][16][32];   // per-wave private

  bf16x8 qf0 = *(const bf16x8*)&Q[(qbase + col) * 64 + quad * 8];
  bf16x8 qf1 = *(const bf16x8*)&Q[(qbase + col) * 64 + quad * 8 + 32];

  f32x4 o0 = {0.f, 0.f, 0.f, 0.f}, o1 = o0, o2 = o0, o3 = o0;
  float mrow[4] = {-1e30f, -1e30f, -1e30f, -1e30f};
  float lrow[4] = {0.f, 0.f, 0.f, 0.f};
  const float scale = 0.125f;

  const int nchunks = (qbase + 47) >> 5;
  for (int c = 0; c < nchunks; ++c) {
    const int k0 = c << 5;
    f32x4 s0 = {0.f, 0.f, 0.f, 0.f}, s1 = s0;
    {
      const u16* kp0 = &Kh[(k0 + col) * 64 + quad * 8];
      s0 = mfma16(qf0, *(const bf16x8*)kp0, s0);
      s0 = mfma16(qf1, *(const bf16x8*)(kp0 + 32), s0);
      const u16* kp1 = kp0 + 16 * 64;
      s1 = mfma16(qf0, *(const bf16x8*)kp1, s1);
      s1 = mfma16(qf1, *(const bf16x8*)(kp1 + 32), s1);
    }
    const bool last = (c == nchunks - 1);
    float p0[4], p1[4], mx[4];
#pragma unroll
    for (int r = 0; r < 4; ++r) {
      float a = s0[r] * scale, b = s1[r] * scale;
      if (last) {
        int q = qbase + quad * 4 + r;
        if (k0 + col > q) a = -1e30f;
        if (k0 + 16 + col > q) b = -1e30f;
      }
      p0[r] = a; p1[r] = b;
      mx[r] = fmaxf(a, b);
    }
#pragma unroll
    for (int m = 1; m <= 8; m <<= 1)
#pragma unroll
      for (int r = 0; r < 4; ++r)
        mx[r] = fmaxf(mx[r], __shfl_xor(mx[r], m));
    float alpha[4];
#pragma unroll
    for (int r = 0; r < 4; ++r) {
      float mn = fmaxf(mrow[r], mx[r]);
      alpha[r] = __expf(mrow[r] - mn);
      mrow[r] = mn;
      p0[r] = __expf(p0[r] - mn);
      p1[r] = __expf(p1[r] - mn);
    }
    float sm[4];
#pragma unroll
    for (int r = 0; r < 4; ++r) sm[r] = p0[r] + p1[r];
#pragma unroll
    for (int m = 1; m <= 8; m <<= 1)
#pragma unroll
      for (int r = 0; r < 4; ++r) sm[r] += __shfl_xor(sm[r], m);
#pragma unroll
    for (int r = 0; r < 4; ++r) {
      lrow[r] = lrow[r] * alpha[r] + sm[r];
      o0[r] *= alpha[r]; o1[r] *= alpha[r];
      o2[r] *= alpha[r]; o3[r] *= alpha[r];
    }
    // P (C-layout) -> LDS -> A-layout fragment (per-wave, no barrier needed)
#pragma unroll
    for (int r = 0; r < 4; ++r) {
      Pld[wave][quad * 4 + r][col] = f2bf(p0[r]);
      Pld[wave][quad * 4 + r][col + 16] = f2bf(p1[r]);
    }
    bf16x8 pa = *(const bf16x8*)&Pld[wave][col][quad * 8];
    const u16* vp = &Vt[col * S + k0 + quad * 8];
    o0 = mfma16(pa, *(const bf16x8*)vp, o0);
    o1 = mfma16(pa, *(const bf16x8*)(vp + 16 * S), o1);
    o2 = mfma16(pa, *(const bf16x8*)(vp + 32 * S), o2);
    o3 = mfma16(pa, *(const bf16x8*)(vp + 48 * S), o3);
  }
#pragma unroll
  for (int r = 0; r < 4; ++r) {
    float inv = 1.0f / lrow[r];
    int row = qbase + quad * 4 + r;
    u16* dst = &attn[(size_t)row * DMODEL + h * 64 + col];
    dst[0]  = f2bf(o0[r] * inv);
    dst[16] = f2bf(o1[r] * inv);
    dst[32] = f2bf(o2[r] * inv);
    dst[48] = f2bf(o3[r] * inv);
  }
}

extern "C" void kernel_launch(void* const* d_in, const int* in_sizes, int n_in,
                              void* d_out, int out_size, void* d_ws,
                              size_t ws_size, hipStream_t stream) {
  const float* x = (const float*)d_in[0];
  const int* tokpos = (const int*)d_in[1];
  const float* wqkv = (const float*)d_in[2];
  const float* wo = (const float*)d_in[3];
  float* out = (float*)d_out;

  char* ws = (char*)d_ws;
  u16* xb    = (u16*)(ws);
  u16* wqkvb = (u16*)(ws + ((size_t)8 << 20));
  u16* wob   = (u16*)(ws + ((size_t)14 << 20));
  u16* qb    = (u16*)(ws + ((size_t)16 << 20));
  u16* kb    = (u16*)(ws + ((size_t)24 << 20));
  u16* vbT   = (u16*)(ws + ((size_t)32 << 20));
  u16* attn  = (u16*)(ws + ((size_t)40 << 20));
  float2* cstab = (float2*)(ws + ((size_t)48 << 20));

  rope_tab_kernel<<<dim3(512), dim3(256), 0, stream>>>(tokpos, cstab);
  cvt_kernel<<<dim3(4096), dim3(256), 0, stream>>>(x, xb, 1 << 20);
  cvt_kernel<<<dim3(3072), dim3(256), 0, stream>>>(wqkv, wqkvb, 3 << 18);
  cvt_kernel<<<dim3(1024), dim3(256), 0, stream>>>(wo, wob, 1 << 18);
  // qkv^T GEMM: M = 3072 (e) x N = 4096 (s), fused RoPE epilogue
  gemm128_kernel<1><<<dim3(24, 32), dim3(256), 0, stream>>>(
      wqkvb, xb, 4096, nullptr, qb, kb, vbT, cstab);
  flash_kernel<<<dim3(64, 16), dim3(256), 0, stream>>>(qb, kb, vbT, attn);
  // out GEMM: M = 4096 (s) x N = 1024 (e), fp32 out
  gemm128_kernel<0><<<dim3(32, 8), dim3(256), 0, stream>>>(
      attn, wob, 1024, out, nullptr, nullptr, nullptr, nullptr);
}

// Round 2
// 411.174 us; speedup vs baseline: 1.5209x; 1.5209x over previous
//
#include <hip/hip_runtime.h>
#include <stdint.h>

typedef unsigned short u16;
typedef __attribute__((ext_vector_type(8))) short bf16x8;
typedef __attribute__((ext_vector_type(4))) float f32x4;

#define LN_THETA 9.210340371976184f
#define SLEN 4096
#define DMODEL 1024

__device__ __forceinline__ u16 f2bf(float f) {
  union { float f; unsigned u; } v; v.f = f;
  unsigned u = v.u;
  return (u16)((u + 0x7FFFu + ((u >> 16) & 1u)) >> 16);
}

__device__ __forceinline__ f32x4 mfma16(bf16x8 a, bf16x8 b, f32x4 c) {
  return __builtin_amdgcn_mfma_f32_16x16x32_bf16(a, b, c, 0, 0, 0);
}

__device__ __forceinline__ void async16(const u16* g, u16* l) {
  __builtin_amdgcn_global_load_lds(
      (const __attribute__((address_space(1))) unsigned int*)g,
      (__attribute__((address_space(3))) unsigned int*)l, 16, 0, 0);
}

// ---- RoPE table: tab[s*32+i] = (cos, sin)(pos[s] * theta^(-2i/64))
__global__ void rope_tab_kernel(const int* __restrict__ tokpos,
                                float2* __restrict__ tab) {
  int t = blockIdx.x * 256 + threadIdx.x;   // 0 .. 4096*32-1
  int s = t >> 5, i = t & 31;
  float inv = expf(-(float)(2 * i) * (LN_THETA / 64.0f));
  float ang = (float)tokpos[s] * inv;
  float sn, cs;
  sincosf(ang, &sn, &cs);
  tab[t] = make_float2(cs, sn);
}

// ---- fp32 -> bf16 (RNE), 4 elems/thread
__global__ void cvt_kernel(const float* __restrict__ src, u16* __restrict__ dst,
                           int n4) {
  int i = blockIdx.x * 256 + threadIdx.x;
  if (i >= n4) return;
  float4 v = ((const float4*)src)[i];
  ushort4 o;
  o.x = f2bf(v.x); o.y = f2bf(v.y); o.z = f2bf(v.z); o.w = f2bf(v.w);
  ((ushort4*)dst)[i] = o;
}

// ---- 128x128 bf16 MFMA GEMM, D = A(MxK) . B(NxK)^T, K=1024.
// EPI 0: plain fp32 store, D[row][col] -> outf, ld = N
// EPI 1: A = W_qkv (rows = e), B = x (rows = s). Fused RoPE, scatter q/k/vT.
template <int EPI>
__global__ __launch_bounds__(256) void gemm128_kernel(
    const u16* __restrict__ A, const u16* __restrict__ B, int N,
    float* __restrict__ outf, u16* __restrict__ qb, u16* __restrict__ kb,
    u16* __restrict__ vbT, const float2* __restrict__ cstab) {
  const int K = 1024;
  __shared__ __align__(16) u16 As[128][32];
  __shared__ __align__(16) u16 Bs[128][32];
  const int tid = threadIdx.x;
  const int wave = tid >> 6, lane = tid & 63;
  const int quad = lane >> 4, col = lane & 15;
  const int rowBase = blockIdx.x * 128;
  const int colBase = blockIdx.y * 128;
  const int wm = (wave >> 1) * 64, wn = (wave & 1) * 64;

  const int sRow = wave * 32 + (lane >> 2);
  const int sK = (lane & 3) * 8;
  const u16* gA = A + (size_t)(rowBase + sRow) * K + sK;
  const u16* gB = B + (size_t)(colBase + sRow) * K + sK;

  f32x4 acc[4][4];
#pragma unroll
  for (int i = 0; i < 4; ++i)
#pragma unroll
    for (int j = 0; j < 4; ++j)
      acc[i][j] = f32x4{0.f, 0.f, 0.f, 0.f};

  for (int kk = 0; kk < K; kk += 32) {
    __syncthreads();
    async16(gA + kk, &As[sRow][sK]);
    async16(gA + kk + 16 * K, &As[sRow + 16][sK]);
    async16(gB + kk, &Bs[sRow][sK]);
    async16(gB + kk + 16 * K, &Bs[sRow + 16][sK]);
    __syncthreads();
    bf16x8 af[4], bfr[4];
#pragma unroll
    for (int i = 0; i < 4; ++i)
      af[i] = *(const bf16x8*)&As[wm + i * 16 + col][quad * 8];
#pragma unroll
    for (int j = 0; j < 4; ++j)
      bfr[j] = *(const bf16x8*)&Bs[wn + j * 16 + col][quad * 8];
#pragma unroll
    for (int i = 0; i < 4; ++i)
#pragma unroll
      for (int j = 0; j < 4; ++j)
        acc[i][j] = mfma16(af[i], bfr[j], acc[i][j]);
  }

  if (EPI == 0) {
#pragma unroll
    for (int i = 0; i < 4; ++i) {
      int r0 = rowBase + wm + i * 16 + quad * 4;
#pragma unroll
      for (int j = 0; j < 4; ++j) {
        int cc = colBase + wn + j * 16 + col;
#pragma unroll
        for (int r = 0; r < 4; ++r)
          outf[(size_t)(r0 + r) * N + cc] = acc[i][j][r];
      }
    }
  } else {
#pragma unroll
    for (int j = 0; j < 4; ++j) {
      int s = colBase + wn + j * 16 + col;
#pragma unroll
      for (int i = 0; i < 4; ++i) {
        int e0 = rowBase + wm + i * 16 + quad * 4;
        int sec = e0 >> 10;          // 0=q 1=k 2=v
        int eh = e0 & 1023;
        int hh = eh >> 6, d = eh & 63;   // d % 4 == 0
        float v0 = acc[i][j][0], v1 = acc[i][j][1];
        float v2 = acc[i][j][2], v3 = acc[i][j][3];
        if (sec < 2) {
          float2 cs0 = cstab[s * 32 + (d >> 1)];
          float2 cs1 = cstab[s * 32 + (d >> 1) + 1];
          float r0 = v0 * cs0.x - v1 * cs0.y;
          float r1 = v1 * cs0.x + v0 * cs0.y;
          float r2 = v2 * cs1.x - v3 * cs1.y;
          float r3 = v3 * cs1.x + v2 * cs1.y;
          u16* dst = (sec == 0 ? qb : kb) + ((size_t)hh * SLEN + s) * 64 + d;
          dst[0] = f2bf(r0); dst[1] = f2bf(r1);
          dst[2] = f2bf(r2); dst[3] = f2bf(r3);
        } else {
          u16* dst = vbT + ((size_t)hh * 64 + d) * SLEN + s;
          dst[0] = f2bf(v0);
          dst[SLEN] = f2bf(v1);
          dst[2 * SLEN] = f2bf(v2);
          dst[3 * SLEN] = f2bf(v3);
        }
      }
    }
  }
}

// ---- causal flash attention v2
// grid (16 heads, 32 tile-pairs); block = 4 waves; wave = 16 q rows.
// block (h,t) does 64-row q-tile t then tile 63-t => 65 key-chunks per wave.
// 64-key chunks, register double-buffered K prefetch, V issued early.
__global__ __launch_bounds__(256) void flash_kernel(
    const u16* __restrict__ qbuf, const u16* __restrict__ kbuf,
    const u16* __restrict__ vbT, u16* __restrict__ attn) {
  const int S = SLEN;
  const int h = blockIdx.x;
  const int t = blockIdx.y;
  const int wave = threadIdx.x >> 6, lane = threadIdx.x & 63;
  const int quad = lane >> 4, col = lane & 15;
  const u16* Q = qbuf + (size_t)h * S * 64;
  const u16* Kh = kbuf + (size_t)h * S * 64;
  const u16* Vt = vbT + (size_t)h * 64 * S;
  const float scale = 0.125f;

  __shared__ __align__(16) u16 Pld[4][16][72];   // per-wave private, padded

  for (int pass = 0; pass < 2; ++pass) {
    const int tile = pass ? (63 - t) : t;
    const int nch = tile + 1;                    // 64-key chunks
    const int qbase = tile * 64 + wave * 16;

    bf16x8 qf0 = *(const bf16x8*)&Q[(size_t)(qbase + col) * 64 + quad * 8];
    bf16x8 qf1 = *(const bf16x8*)&Q[(size_t)(qbase + col) * 64 + quad * 8 + 32];

    f32x4 o[4];
#pragma unroll
    for (int n = 0; n < 4; ++n) o[n] = f32x4{0.f, 0.f, 0.f, 0.f};
    float mrow[4] = {-1e30f, -1e30f, -1e30f, -1e30f};
    float lrow[4] = {0.f, 0.f, 0.f, 0.f};

    auto loadK = [&](bf16x8* kf, int c) {
#pragma unroll
      for (int j = 0; j < 4; ++j) {
        const u16* kp = &Kh[(size_t)(c * 64 + 16 * j + col) * 64 + quad * 8];
        kf[2 * j] = *(const bf16x8*)kp;
        kf[2 * j + 1] = *(const bf16x8*)(kp + 32);
      }
    };

    auto process = [&](const bf16x8* kf, int c, bool last) {
      const int k0 = c * 64;
      // V loads for this chunk — consumed only after the softmax chain
      bf16x8 vf[8];
#pragma unroll
      for (int n = 0; n < 4; ++n) {
        const u16* vp = &Vt[(size_t)(16 * n + col) * S + k0 + quad * 8];
        vf[2 * n] = *(const bf16x8*)vp;
        vf[2 * n + 1] = *(const bf16x8*)(vp + 32);
      }
      f32x4 s[4];
#pragma unroll
      for (int j = 0; j < 4; ++j)
        s[j] = mfma16(qf1, kf[2 * j + 1],
                      mfma16(qf0, kf[2 * j], f32x4{0.f, 0.f, 0.f, 0.f}));
      float p[4][4], mx[4];
#pragma unroll
      for (int r = 0; r < 4; ++r) {
        const int q = qbase + quad * 4 + r;
#pragma unroll
        for (int j = 0; j < 4; ++j) {
          float a = s[j][r] * scale;
          if (last && (k0 + 16 * j + col > q)) a = -1e30f;
          p[j][r] = a;
        }
        mx[r] = fmaxf(fmaxf(p[0][r], p[1][r]), fmaxf(p[2][r], p[3][r]));
      }
#pragma unroll
      for (int m = 1; m <= 8; m <<= 1)
#pragma unroll
        for (int r = 0; r < 4; ++r)
          mx[r] = fmaxf(mx[r], __shfl_xor(mx[r], m));
      float alpha[4], sm[4];
#pragma unroll
      for (int r = 0; r < 4; ++r) {
        float mn = fmaxf(mrow[r], mx[r]);
        alpha[r] = __expf(mrow[r] - mn);
        mrow[r] = mn;
#pragma unroll
        for (int j = 0; j < 4; ++j) p[j][r] = __expf(p[j][r] - mn);
        sm[r] = (p[0][r] + p[1][r]) + (p[2][r] + p[3][r]);
      }
#pragma unroll
      for (int m = 1; m <= 8; m <<= 1)
#pragma unroll
        for (int r = 0; r < 4; ++r) sm[r] += __shfl_xor(sm[r], m);
#pragma unroll
      for (int r = 0; r < 4; ++r) {
        lrow[r] = lrow[r] * alpha[r] + sm[r];
#pragma unroll
        for (int n = 0; n < 4; ++n) o[n][r] *= alpha[r];
      }
      // P (C-layout) -> padded LDS -> A-layout fragments (per-wave private)
#pragma unroll
      for (int j = 0; j < 4; ++j)
#pragma unroll
        for (int r = 0; r < 4; ++r)
          Pld[wave][quad * 4 + r][16 * j + col] = f2bf(p[j][r]);
      bf16x8 pa0 = *(const bf16x8*)&Pld[wave][col][quad * 8];
      bf16x8 pa1 = *(const bf16x8*)&Pld[wave][col][quad * 8 + 32];
#pragma unroll
      for (int n = 0; n < 4; ++n)
        o[n] = mfma16(pa1, vf[2 * n + 1], mfma16(pa0, vf[2 * n], o[n]));
    };

    bf16x8 kfA[8], kfB[8];
    loadK(kfA, 0);
    for (int c = 0; c < nch; c += 2) {
      bool lastA = (c == nch - 1);
      if (!lastA) loadK(kfB, c + 1);
      process(kfA, c, lastA);
      if (lastA) break;
      bool lastB = (c + 1 == nch - 1);
      if (!lastB) loadK(kfA, c + 2);
      process(kfB, c + 1, lastB);
    }

#pragma unroll
    for (int r = 0; r < 4; ++r) {
      float inv = 1.0f / lrow[r];
      int row = qbase + quad * 4 + r;
      u16* dst = &attn[(size_t)row * DMODEL + h * 64 + col];
#pragma unroll
      for (int n = 0; n < 4; ++n) dst[16 * n] = f2bf(o[n][r] * inv);
    }
  }
}

extern "C" void kernel_launch(void* const* d_in, const int* in_sizes, int n_in,
                              void* d_out, int out_size, void* d_ws,
                              size_t ws_size, hipStream_t stream) {
  const float* x = (const float*)d_in[0];
  const int* tokpos = (const int*)d_in[1];
  const float* wqkv = (const float*)d_in[2];
  const float* wo = (const float*)d_in[3];
  float* out = (float*)d_out;

  char* ws = (char*)d_ws;
  u16* xb    = (u16*)(ws);
  u16* wqkvb = (u16*)(ws + ((size_t)8 << 20));
  u16* wob   = (u16*)(ws + ((size_t)14 << 20));
  u16* qb    = (u16*)(ws + ((size_t)16 << 20));
  u16* kb    = (u16*)(ws + ((size_t)24 << 20));
  u16* vbT   = (u16*)(ws + ((size_t)32 << 20));
  u16* attn  = (u16*)(ws + ((size_t)40 << 20));
  float2* cstab = (float2*)(ws + ((size_t)48 << 20));

  rope_tab_kernel<<<dim3(512), dim3(256), 0, stream>>>(tokpos, cstab);
  cvt_kernel<<<dim3(4096), dim3(256), 0, stream>>>(x, xb, 1 << 20);
  cvt_kernel<<<dim3(3072), dim3(256), 0, stream>>>(wqkv, wqkvb, 3 << 18);
  cvt_kernel<<<dim3(1024), dim3(256), 0, stream>>>(wo, wob, 1 << 18);
  // qkv^T GEMM: M = 3072 (e) x N = 4096 (s), fused RoPE epilogue
  gemm128_kernel<1><<<dim3(24, 32), dim3(256), 0, stream>>>(
      wqkvb, xb, 4096, nullptr, qb, kb, vbT, cstab);
  flash_kernel<<<dim3(16, 32), dim3(256), 0, stream>>>(qb, kb, vbT, attn);
  // out GEMM: M = 4096 (s) x N = 1024 (e), fp32 out
  gemm128_kernel<0><<<dim3(32, 8), dim3(256), 0, stream>>>(
      attn, wob, 1024, out, nullptr, nullptr, nullptr, nullptr);
}